// Round 1
// baseline (161.192 us; speedup 1.0000x reference)
//
#include <hip/hip_runtime.h>
#include <stdint.h>

// Quant3Linear GEMV: y = x @ (scales.T * unpack3(qweight) - zeros.T) + bias
//   x: (1, 8192) f32 | qweight: (768, 28672) i32 | scales,zeros: (28672,1) | bias: (28672,)
// Decomposition: y[o] = scales[o]*dot(x, q[:,o]) - zeros[o]*sum(x) + bias[o]
//
// Stage A (q3_partial): split-K=64 (1792 blocks -> 7 blocks/CU, 28 waves/CU),
//   4 columns/thread via dwordx4 qweight loads, depth-1 software prefetch so
//   next group's 3 loads are in flight under current group's 384 FMAs.
// Stage B (q3_finish): 64-way partial reduce + bias - zeros*sum(x), one write/o.

constexpr int O_FEAT  = 28672;
constexpr int IN_FEAT = 8192;
constexpr int NGROUP  = IN_FEAT / 32;   // 256 groups (3 packed int32 rows each)
constexpr int SPLIT   = 64;             // split-K factor (was 32)
constexpr int GPB     = NGROUP / SPLIT; // 4 groups per thread
constexpr int O4      = O_FEAT / 4;     // uint4 columns per packed row

// Unpack one column-group (32 3-bit codes in w0,w1,w2; GPTQ packing) and
// accumulate dot with xv[0..31]. 3 internal chains cover FMA latency.
__device__ __forceinline__ void dot_group(uint32_t w0, uint32_t w1, uint32_t w2,
                                          const float xv[32], float& acc) {
  float a0 = acc, a1 = 0.f, a2 = 0.f;
  #pragma unroll
  for (int j = 0; j < 10; ++j) a0 += xv[j] * (float)((w0 >> (3 * j)) & 7u);
  a0 += xv[10] * (float)((w0 >> 30) | ((w1 & 1u) << 2));
  #pragma unroll
  for (int j = 0; j < 10; ++j) a1 += xv[11 + j] * (float)((w1 >> (3 * j + 1)) & 7u);
  a1 += xv[21] * (float)((w1 >> 31) | ((w2 & 3u) << 1));
  #pragma unroll
  for (int j = 0; j < 10; ++j) a2 += xv[22 + j] * (float)((w2 >> (3 * j + 2)) & 7u);
  acc = a0 + (a1 + a2);
}

__global__ __launch_bounds__(256, 4) void q3_partial(const float* __restrict__ x,
                                                     const uint4* __restrict__ qw4,
                                                     float* __restrict__ part) {
  const int tcol4 = blockIdx.x * 256 + threadIdx.x;  // index in units of 4 columns
  const int g0    = blockIdx.y * GPB;
  const uint4* qp = qw4 + (size_t)(3 * g0) * O4 + tcol4;
  const float* xp = x + g0 * 32;                     // block-uniform -> s_load path
  float acc0 = 0.f, acc1 = 0.f, acc2 = 0.f, acc3 = 0.f;

  // Depth-1 prefetch: group g+1's 3 rows load while group g's FMAs run.
  uint4 na = qp[0], nb = qp[O4], nc = qp[2 * O4];
  #pragma unroll
  for (int g = 0; g < GPB; ++g) {
    const uint4 wa = na, wb = nb, wc = nc;
    if (g + 1 < GPB) {
      qp += 3 * O4;
      na = qp[0]; nb = qp[O4]; nc = qp[2 * O4];
    }

    float xv[32];
    const float4* x4 = reinterpret_cast<const float4*>(xp + g * 32);
    #pragma unroll
    for (int u = 0; u < 8; ++u) {
      float4 t = x4[u];
      xv[4 * u + 0] = t.x; xv[4 * u + 1] = t.y;
      xv[4 * u + 2] = t.z; xv[4 * u + 3] = t.w;
    }

    dot_group(wa.x, wb.x, wc.x, xv, acc0);  // 4 independent chains
    dot_group(wa.y, wb.y, wc.y, xv, acc1);
    dot_group(wa.z, wb.z, wc.z, xv, acc2);
    dot_group(wa.w, wb.w, wc.w, xv, acc3);
  }

  float4 r = make_float4(acc0, acc1, acc2, acc3);
  reinterpret_cast<float4*>(part)[(size_t)blockIdx.y * O4 + tcol4] = r;
}

__global__ __launch_bounds__(256) void q3_finish(const float* __restrict__ x,
                                                 const float* __restrict__ part,
                                                 const float* __restrict__ scales,
                                                 const float* __restrict__ zeros,
                                                 const float* __restrict__ bias,
                                                 float* __restrict__ out) {
  // Block-redundant reduction of x (32 KB, L2-resident).
  float s = 0.f;
  const float4* x4 = reinterpret_cast<const float4*>(x);
  for (int i = threadIdx.x; i < IN_FEAT / 4; i += 256) {
    float4 t = x4[i];
    s += (t.x + t.y) + (t.z + t.w);
  }
  #pragma unroll
  for (int off = 32; off > 0; off >>= 1) s += __shfl_down(s, off, 64);
  __shared__ float ls[4];
  if ((threadIdx.x & 63) == 0) ls[threadIdx.x >> 6] = s;
  __syncthreads();
  float S = (ls[0] + ls[1]) + (ls[2] + ls[3]);

  int o = blockIdx.x * 256 + threadIdx.x;
  float s0 = 0.f, s1 = 0.f, s2 = 0.f, s3 = 0.f;
  #pragma unroll
  for (int y = 0; y < SPLIT; y += 4) {
    s0 += part[(size_t)(y + 0) * O_FEAT + o];
    s1 += part[(size_t)(y + 1) * O_FEAT + o];
    s2 += part[(size_t)(y + 2) * O_FEAT + o];
    s3 += part[(size_t)(y + 3) * O_FEAT + o];
  }
  float sum = (s0 + s1) + (s2 + s3);
  out[o] = scales[o] * sum - zeros[o] * S + bias[o];
}

extern "C" void kernel_launch(void* const* d_in, const int* in_sizes, int n_in,
                              void* d_out, int out_size, void* d_ws, size_t ws_size,
                              hipStream_t stream) {
  const float* x      = (const float*)d_in[0];
  const uint4* qw4    = (const uint4*)d_in[1];
  const float* scales = (const float*)d_in[2];
  const float* zeros  = (const float*)d_in[3];
  const float* bias   = (const float*)d_in[4];
  float*       out    = (float*)d_out;
  float*       part   = (float*)d_ws;   // SPLIT * O_FEAT floats = 7.34 MB

  q3_partial<<<dim3(O_FEAT / (256 * 4), SPLIT), dim3(256), 0, stream>>>(x, qw4, part);
  q3_finish<<<dim3(O_FEAT / 256), dim3(256), 0, stream>>>(x, part, scales, zeros, bias, out);
}

// Round 2
// 161.129 us; speedup vs baseline: 1.0004x; 1.0004x over previous
//
#include <hip/hip_runtime.h>
#include <stdint.h>

// Quant3Linear GEMV: y = x @ (scales.T * unpack3(qweight) - zeros.T) + bias
//   x: (1, 8192) f32 | qweight: (768, 28672) i32 | scales,zeros: (28672,1) | bias: (28672,)
// Decomposition: y[o] = scales[o]*dot(x, q[:,o]) - zeros[o]*sum(x) + bias[o]
//
// Stage A (q3_partial): split-K=64 (1792 blocks -> 7 blocks/CU, 28 waves/CU),
//   4 columns/thread via dwordx4 qweight loads, depth-1 software prefetch so
//   next group's 3 loads are in flight under current group's 384 FMAs.
//   NO min-waves launch bound: a 128-VGPR cap forces xv[32]+prefetch spills
//   (round-1 regression 145->161 us); grid already gives 7 blocks/CU.
// Stage B (q3_finish): 64-way partial reduce + bias - zeros*sum(x), one write/o.

constexpr int O_FEAT  = 28672;
constexpr int IN_FEAT = 8192;
constexpr int NGROUP  = IN_FEAT / 32;   // 256 groups (3 packed int32 rows each)
constexpr int SPLIT   = 64;             // split-K factor
constexpr int GPB     = NGROUP / SPLIT; // 4 groups per thread
constexpr int O4      = O_FEAT / 4;     // uint4 columns per packed row

// Unpack one column-group (32 3-bit codes in w0,w1,w2; GPTQ packing) and
// accumulate dot with xv[0..31]. 3 internal chains cover FMA latency.
__device__ __forceinline__ void dot_group(uint32_t w0, uint32_t w1, uint32_t w2,
                                          const float xv[32], float& acc) {
  float a0 = acc, a1 = 0.f, a2 = 0.f;
  #pragma unroll
  for (int j = 0; j < 10; ++j) a0 += xv[j] * (float)((w0 >> (3 * j)) & 7u);
  a0 += xv[10] * (float)((w0 >> 30) | ((w1 & 1u) << 2));
  #pragma unroll
  for (int j = 0; j < 10; ++j) a1 += xv[11 + j] * (float)((w1 >> (3 * j + 1)) & 7u);
  a1 += xv[21] * (float)((w1 >> 31) | ((w2 & 3u) << 1));
  #pragma unroll
  for (int j = 0; j < 10; ++j) a2 += xv[22 + j] * (float)((w2 >> (3 * j + 2)) & 7u);
  acc = a0 + (a1 + a2);
}

__global__ __launch_bounds__(256) void q3_partial(const float* __restrict__ x,
                                                  const uint4* __restrict__ qw4,
                                                  float* __restrict__ part) {
  const int tcol4 = blockIdx.x * 256 + threadIdx.x;  // index in units of 4 columns
  const int g0    = blockIdx.y * GPB;
  const uint4* qp = qw4 + (size_t)(3 * g0) * O4 + tcol4;
  const float* xp = x + g0 * 32;                     // block-uniform -> s_load path
  float acc0 = 0.f, acc1 = 0.f, acc2 = 0.f, acc3 = 0.f;

  // Depth-1 prefetch: group g+1's 3 rows load while group g's FMAs run.
  uint4 na = qp[0], nb = qp[O4], nc = qp[2 * O4];
  #pragma unroll
  for (int g = 0; g < GPB; ++g) {
    const uint4 wa = na, wb = nb, wc = nc;
    if (g + 1 < GPB) {
      qp += 3 * O4;
      na = qp[0]; nb = qp[O4]; nc = qp[2 * O4];
    }

    float xv[32];
    const float4* x4 = reinterpret_cast<const float4*>(xp + g * 32);
    #pragma unroll
    for (int u = 0; u < 8; ++u) {
      float4 t = x4[u];
      xv[4 * u + 0] = t.x; xv[4 * u + 1] = t.y;
      xv[4 * u + 2] = t.z; xv[4 * u + 3] = t.w;
    }

    dot_group(wa.x, wb.x, wc.x, xv, acc0);  // 4 independent chains
    dot_group(wa.y, wb.y, wc.y, xv, acc1);
    dot_group(wa.z, wb.z, wc.z, xv, acc2);
    dot_group(wa.w, wb.w, wc.w, xv, acc3);
  }

  float4 r = make_float4(acc0, acc1, acc2, acc3);
  reinterpret_cast<float4*>(part)[(size_t)blockIdx.y * O4 + tcol4] = r;
}

__global__ __launch_bounds__(256) void q3_finish(const float* __restrict__ x,
                                                 const float* __restrict__ part,
                                                 const float* __restrict__ scales,
                                                 const float* __restrict__ zeros,
                                                 const float* __restrict__ bias,
                                                 float* __restrict__ out) {
  // Block-redundant reduction of x (32 KB, L2-resident).
  float s = 0.f;
  const float4* x4 = reinterpret_cast<const float4*>(x);
  for (int i = threadIdx.x; i < IN_FEAT / 4; i += 256) {
    float4 t = x4[i];
    s += (t.x + t.y) + (t.z + t.w);
  }
  #pragma unroll
  for (int off = 32; off > 0; off >>= 1) s += __shfl_down(s, off, 64);
  __shared__ float ls[4];
  if ((threadIdx.x & 63) == 0) ls[threadIdx.x >> 6] = s;
  __syncthreads();
  float S = (ls[0] + ls[1]) + (ls[2] + ls[3]);

  int o = blockIdx.x * 256 + threadIdx.x;
  float s0 = 0.f, s1 = 0.f, s2 = 0.f, s3 = 0.f;
  #pragma unroll
  for (int y = 0; y < SPLIT; y += 4) {
    s0 += part[(size_t)(y + 0) * O_FEAT + o];
    s1 += part[(size_t)(y + 1) * O_FEAT + o];
    s2 += part[(size_t)(y + 2) * O_FEAT + o];
    s3 += part[(size_t)(y + 3) * O_FEAT + o];
  }
  float sum = (s0 + s1) + (s2 + s3);
  out[o] = scales[o] * sum - zeros[o] * S + bias[o];
}

extern "C" void kernel_launch(void* const* d_in, const int* in_sizes, int n_in,
                              void* d_out, int out_size, void* d_ws, size_t ws_size,
                              hipStream_t stream) {
  const float* x      = (const float*)d_in[0];
  const uint4* qw4    = (const uint4*)d_in[1];
  const float* scales = (const float*)d_in[2];
  const float* zeros  = (const float*)d_in[3];
  const float* bias   = (const float*)d_in[4];
  float*       out    = (float*)d_out;
  float*       part   = (float*)d_ws;   // SPLIT * O_FEAT floats = 7.34 MB

  q3_partial<<<dim3(O_FEAT / (256 * 4), SPLIT), dim3(256), 0, stream>>>(x, qw4, part);
  q3_finish<<<dim3(O_FEAT / 256), dim3(256), 0, stream>>>(x, part, scales, zeros, bias, out);
}

// Round 3
// 145.519 us; speedup vs baseline: 1.1077x; 1.1073x over previous
//
#include <hip/hip_runtime.h>
#include <stdint.h>

// Quant3Linear GEMV: y = x @ (scales.T * unpack3(qweight) - zeros.T) + bias
//   x: (1, 8192) f32 | qweight: (768, 28672) i32 | scales,zeros: (28672,1) | bias: (28672,)
// Decomposition: y[o] = scales[o]*dot(x, q[:,o]) - zeros[o]*sum(x) + bias[o]
//
// Stage A (q3_partial): split-K=32 (896 blocks), 4 columns/thread via dwordx4
//   qweight loads. x staged in LDS (1 KB/block) so the inner loop's only vmem
//   is the 3 qweight rows -> per-iteration wait is vmcnt(3) with a rolled-loop
//   depth-1 prefetch (x reads ride lgkmcnt instead of forcing vmcnt(0)).
//   History: SPLIT=64 + full-unroll prefetch regressed 145->161 us (R1/R2);
//   128-VGPR cap was ruled innocent by A/B.
// Stage B (q3_finish): 32-way partial reduce + bias - zeros*sum(x), one write/o.

constexpr int O_FEAT  = 28672;
constexpr int IN_FEAT = 8192;
constexpr int NGROUP  = IN_FEAT / 32;   // 256 groups (3 packed int32 rows each)
constexpr int SPLIT   = 32;             // split-K factor
constexpr int GPB     = NGROUP / SPLIT; // 8 groups per thread
constexpr int O4      = O_FEAT / 4;     // uint4 columns per packed row

// Unpack one column-group (32 3-bit codes in w0,w1,w2; GPTQ packing) and
// accumulate dot with xv[0..31]. 3 internal chains cover FMA latency.
__device__ __forceinline__ void dot_group(uint32_t w0, uint32_t w1, uint32_t w2,
                                          const float xv[32], float& acc) {
  float a0 = acc, a1 = 0.f, a2 = 0.f;
  #pragma unroll
  for (int j = 0; j < 10; ++j) a0 += xv[j] * (float)((w0 >> (3 * j)) & 7u);
  a0 += xv[10] * (float)((w0 >> 30) | ((w1 & 1u) << 2));
  #pragma unroll
  for (int j = 0; j < 10; ++j) a1 += xv[11 + j] * (float)((w1 >> (3 * j + 1)) & 7u);
  a1 += xv[21] * (float)((w1 >> 31) | ((w2 & 3u) << 1));
  #pragma unroll
  for (int j = 0; j < 10; ++j) a2 += xv[22 + j] * (float)((w2 >> (3 * j + 2)) & 7u);
  acc = a0 + (a1 + a2);
}

__global__ __launch_bounds__(256) void q3_partial(const float* __restrict__ x,
                                                  const uint4* __restrict__ qw4,
                                                  float* __restrict__ part) {
  const int tcol4 = blockIdx.x * 256 + threadIdx.x;  // index in units of 4 columns
  const int g0    = blockIdx.y * GPB;
  const uint4* qp = qw4 + (size_t)(3 * g0) * O4 + tcol4;

  // Stage this block's x chunk (GPB*32 = 256 floats = 1 KB) in LDS: exactly
  // one float per thread. Keeps the hot loop's vmcnt queue qweight-only.
  __shared__ float xs[GPB * 32];
  xs[threadIdx.x] = x[g0 * 32 + threadIdx.x];
  __syncthreads();

  float acc0 = 0.f, acc1 = 0.f, acc2 = 0.f, acc3 = 0.f;

  // Rolled loop, depth-1 qweight prefetch. Last iteration re-loads its own
  // rows (pointer clamped, branchless) -- harmless L1 hit, keeps loads
  // unconditional so the wait before dot_group is vmcnt(3), not vmcnt(0).
  uint4 na = qp[0], nb = qp[O4], nc = qp[2 * O4];
  for (int g = 0; g < GPB; ++g) {
    const uint4 wa = na, wb = nb, wc = nc;
    qp += (g < GPB - 1) ? 3 * O4 : 0;
    na = qp[0]; nb = qp[O4]; nc = qp[2 * O4];

    float xv[32];
    const float4* s4 = reinterpret_cast<const float4*>(&xs[g * 32]);
    #pragma unroll
    for (int u = 0; u < 8; ++u) {
      float4 t = s4[u];
      xv[4 * u + 0] = t.x; xv[4 * u + 1] = t.y;
      xv[4 * u + 2] = t.z; xv[4 * u + 3] = t.w;
    }

    dot_group(wa.x, wb.x, wc.x, xv, acc0);  // 4 independent chains
    dot_group(wa.y, wb.y, wc.y, xv, acc1);
    dot_group(wa.z, wb.z, wc.z, xv, acc2);
    dot_group(wa.w, wb.w, wc.w, xv, acc3);
  }

  float4 r = make_float4(acc0, acc1, acc2, acc3);
  reinterpret_cast<float4*>(part)[(size_t)blockIdx.y * O4 + tcol4] = r;
}

__global__ __launch_bounds__(256) void q3_finish(const float* __restrict__ x,
                                                 const float* __restrict__ part,
                                                 const float* __restrict__ scales,
                                                 const float* __restrict__ zeros,
                                                 const float* __restrict__ bias,
                                                 float* __restrict__ out) {
  // Block-redundant reduction of x (32 KB, L2-resident).
  float s = 0.f;
  const float4* x4 = reinterpret_cast<const float4*>(x);
  for (int i = threadIdx.x; i < IN_FEAT / 4; i += 256) {
    float4 t = x4[i];
    s += (t.x + t.y) + (t.z + t.w);
  }
  #pragma unroll
  for (int off = 32; off > 0; off >>= 1) s += __shfl_down(s, off, 64);
  __shared__ float ls[4];
  if ((threadIdx.x & 63) == 0) ls[threadIdx.x >> 6] = s;
  __syncthreads();
  float S = (ls[0] + ls[1]) + (ls[2] + ls[3]);

  int o = blockIdx.x * 256 + threadIdx.x;
  float s0 = 0.f, s1 = 0.f, s2 = 0.f, s3 = 0.f;
  #pragma unroll
  for (int y = 0; y < SPLIT; y += 4) {
    s0 += part[(size_t)(y + 0) * O_FEAT + o];
    s1 += part[(size_t)(y + 1) * O_FEAT + o];
    s2 += part[(size_t)(y + 2) * O_FEAT + o];
    s3 += part[(size_t)(y + 3) * O_FEAT + o];
  }
  float sum = (s0 + s1) + (s2 + s3);
  out[o] = scales[o] * sum - zeros[o] * S + bias[o];
}

extern "C" void kernel_launch(void* const* d_in, const int* in_sizes, int n_in,
                              void* d_out, int out_size, void* d_ws, size_t ws_size,
                              hipStream_t stream) {
  const float* x      = (const float*)d_in[0];
  const uint4* qw4    = (const uint4*)d_in[1];
  const float* scales = (const float*)d_in[2];
  const float* zeros  = (const float*)d_in[3];
  const float* bias   = (const float*)d_in[4];
  float*       out    = (float*)d_out;
  float*       part   = (float*)d_ws;   // SPLIT * O_FEAT floats = 3.67 MB

  q3_partial<<<dim3(O_FEAT / (256 * 4), SPLIT), dim3(256), 0, stream>>>(x, qw4, part);
  q3_finish<<<dim3(O_FEAT / 256), dim3(256), 0, stream>>>(x, part, scales, zeros, bias, out);
}

// Round 4
// 142.617 us; speedup vs baseline: 1.1302x; 1.0203x over previous
//
#include <hip/hip_runtime.h>
#include <stdint.h>

// Quant3Linear GEMV: y = x @ (scales.T * unpack3(qweight) - zeros.T) + bias
//   x: (1, 8192) f32 | qweight: (768, 28672) i32 | scales,zeros: (28672,1) | bias: (28672,)
// Decomposition: y[o] = scales[o]*dot(x, q[:,o]) - zeros[o]*sum(x) + bias[o]
//
// Stage A (q3_partial): split-K=32 (896 blocks), 4 columns/thread, x staged in
//   LDS, rolled loop + depth-1 qweight prefetch. dot product restructured
//   around element PAIRS so clang emits v_pk_fma_f32 (CDNA4 packed f32):
//   2xbfe + 2xcvt + 1xpk_fma per pair, ~15% fewer VALU issues than scalar.
//   Also emits per-K-range x-sums partS[y] (free: x-chunk already staged).
// Stage B (q3_finish): 448 blocks x 64 cols, 4 waves each sum 8 partials
//   (coalesced 256B rows, chains of 4), LDS cross-wave combine; S from
//   partS (128 B broadcast) instead of a redundant 32 KB x pass.
// History: SPLIT=64 + full-unroll prefetch regressed (R1/R2, organic spill);
//   latency-hiding ruled out (R1 more-TLP worse, R3 prefetch neutral).

typedef float v2f __attribute__((ext_vector_type(2)));

constexpr int O_FEAT  = 28672;
constexpr int IN_FEAT = 8192;
constexpr int NGROUP  = IN_FEAT / 32;   // 256 groups (3 packed int32 rows each)
constexpr int SPLIT   = 32;             // split-K factor
constexpr int GPB     = NGROUP / SPLIT; // 8 groups per thread
constexpr int O4      = O_FEAT / 4;     // uint4 columns per packed row

// Unpack one column-group (32 3-bit codes in w0,w1,w2; GPTQ packing) and
// accumulate dot with xv[0..15] (f32 pairs). Pair-structured so each pair is
// one v_pk_fma_f32; two v2f chains (a0,a1) cover FMA latency.
__device__ __forceinline__ void dot_group_pk(uint32_t w0, uint32_t w1, uint32_t w2,
                                             const v2f xv[16], v2f& acc) {
  v2f a0 = acc, a1 = {0.f, 0.f};
  #pragma unroll
  for (int t = 0; t < 5; ++t) {   // elements 0..9: w0 bits 3j
    v2f q = { (float)((w0 >> (6 * t)) & 7u), (float)((w0 >> (6 * t + 3)) & 7u) };
    (t & 1 ? a1 : a0) += xv[t] * q;
  }
  { // elements 10 (split w0/w1) and 11 (w1 bit 1)
    v2f q = { (float)((w0 >> 30) | ((w1 & 1u) << 2)), (float)((w1 >> 1) & 7u) };
    a1 += xv[5] * q;
  }
  #pragma unroll
  for (int t = 0; t < 4; ++t) {   // elements 12..19: w1 bits 4+3j
    v2f q = { (float)((w1 >> (4 + 6 * t)) & 7u), (float)((w1 >> (7 + 6 * t)) & 7u) };
    (t & 1 ? a1 : a0) += xv[6 + t] * q;
  }
  { // elements 20 (w1 bit 28) and 21 (split w1/w2)
    v2f q = { (float)((w1 >> 28) & 7u), (float)((w1 >> 31) | ((w2 & 3u) << 1)) };
    a0 += xv[10] * q;
  }
  #pragma unroll
  for (int t = 0; t < 5; ++t) {   // elements 22..31: w2 bits 2+3j
    v2f q = { (float)((w2 >> (2 + 6 * t)) & 7u), (float)((w2 >> (5 + 6 * t)) & 7u) };
    (t & 1 ? a1 : a0) += xv[11 + t] * q;
  }
  acc = a0 + a1;
}

__global__ __launch_bounds__(256) void q3_partial(const float* __restrict__ x,
                                                  const uint4* __restrict__ qw4,
                                                  float* __restrict__ part,
                                                  float* __restrict__ partS) {
  const int tcol4 = blockIdx.x * 256 + threadIdx.x;  // index in units of 4 columns
  const int g0    = blockIdx.y * GPB;
  const uint4* qp = qw4 + (size_t)(3 * g0) * O4 + tcol4;

  // Stage this block's x chunk (256 floats = 1 KB) in LDS: one float/thread.
  __shared__ float xs[GPB * 32];
  const float myx = x[g0 * 32 + threadIdx.x];
  xs[threadIdx.x] = myx;

  // Per-K-range x sum -> partS[y]. All 28 bx-blocks of a y-row compute the
  // identical value deterministically; redundant same-value write is benign.
  float s = myx;
  #pragma unroll
  for (int off = 32; off > 0; off >>= 1) s += __shfl_down(s, off, 64);
  __shared__ float ls[4];
  if ((threadIdx.x & 63) == 0) ls[threadIdx.x >> 6] = s;
  __syncthreads();
  if (threadIdx.x == 0) partS[blockIdx.y] = (ls[0] + ls[1]) + (ls[2] + ls[3]);

  v2f acc0 = {0.f, 0.f}, acc1 = {0.f, 0.f}, acc2 = {0.f, 0.f}, acc3 = {0.f, 0.f};

  // Rolled loop, depth-1 qweight prefetch (last iter re-loads own rows: L1 hit).
  uint4 na = qp[0], nb = qp[O4], nc = qp[2 * O4];
  for (int g = 0; g < GPB; ++g) {
    const uint4 wa = na, wb = nb, wc = nc;
    qp += (g < GPB - 1) ? 3 * O4 : 0;
    na = qp[0]; nb = qp[O4]; nc = qp[2 * O4];

    v2f xv[16];
    const float4* s4 = reinterpret_cast<const float4*>(&xs[g * 32]);
    #pragma unroll
    for (int u = 0; u < 8; ++u) {
      float4 t = s4[u];
      xv[2 * u]     = v2f{t.x, t.y};
      xv[2 * u + 1] = v2f{t.z, t.w};
    }

    dot_group_pk(wa.x, wb.x, wc.x, xv, acc0);  // 4 independent chains
    dot_group_pk(wa.y, wb.y, wc.y, xv, acc1);
    dot_group_pk(wa.z, wb.z, wc.z, xv, acc2);
    dot_group_pk(wa.w, wb.w, wc.w, xv, acc3);
  }

  float4 r = make_float4(acc0.x + acc0.y, acc1.x + acc1.y,
                         acc2.x + acc2.y, acc3.x + acc3.y);
  reinterpret_cast<float4*>(part)[(size_t)blockIdx.y * O4 + tcol4] = r;
}

__global__ __launch_bounds__(256) void q3_finish(const float* __restrict__ part,
                                                 const float* __restrict__ partS,
                                                 const float* __restrict__ scales,
                                                 const float* __restrict__ zeros,
                                                 const float* __restrict__ bias,
                                                 float* __restrict__ out) {
  const int q  = threadIdx.x >> 6;   // wave id 0..3 -> partial slice
  const int ol = threadIdx.x & 63;   // column within block
  const int o  = blockIdx.x * 64 + ol;

  // S = sum over 32 per-range sums (128 B, broadcast load).
  float S = 0.f;
  #pragma unroll
  for (int i = 0; i < 8; ++i) {
    float4 t = reinterpret_cast<const float4*>(partS)[i];
    S += (t.x + t.y) + (t.z + t.w);
  }

  // Each wave sums 8 partial rows; lanes read 256 B coalesced per row.
  float s0 = 0.f, s1 = 0.f;
  #pragma unroll
  for (int y = 0; y < 8; y += 2) {
    s0 += part[(size_t)(8 * q + y)     * O_FEAT + o];
    s1 += part[(size_t)(8 * q + y + 1) * O_FEAT + o];
  }
  __shared__ float red[4][64];
  red[q][ol] = s0 + s1;
  __syncthreads();
  if (q == 0) {
    float tot = (red[0][ol] + red[1][ol]) + (red[2][ol] + red[3][ol]);
    out[o] = scales[o] * tot - zeros[o] * S + bias[o];
  }
}

extern "C" void kernel_launch(void* const* d_in, const int* in_sizes, int n_in,
                              void* d_out, int out_size, void* d_ws, size_t ws_size,
                              hipStream_t stream) {
  const float* x      = (const float*)d_in[0];
  const uint4* qw4    = (const uint4*)d_in[1];
  const float* scales = (const float*)d_in[2];
  const float* zeros  = (const float*)d_in[3];
  const float* bias   = (const float*)d_in[4];
  float*       out    = (float*)d_out;
  float*       part   = (float*)d_ws;                       // SPLIT*O_FEAT floats
  float*       partS  = (float*)d_ws + (size_t)SPLIT * O_FEAT;  // + SPLIT floats

  q3_partial<<<dim3(O_FEAT / (256 * 4), SPLIT), dim3(256), 0, stream>>>(x, qw4, part, partS);
  q3_finish<<<dim3(O_FEAT / 64), dim3(256), 0, stream>>>(part, partS, scales, zeros, bias, out);
}